// Round 7
// baseline (41.888 us; speedup 1.0000x reference)
//
#include <hip/hip_runtime.h>
#include <math.h>

// Problem sizes (fixed): B=4, N=512, M=512, D=256
#define BB 4
#define NN 512
#define MM 512
#define DD 256

typedef short  s16x8 __attribute__((ext_vector_type(8)));
typedef __bf16 bf16x8 __attribute__((ext_vector_type(8)));
typedef float  f32x4 __attribute__((ext_vector_type(4)));
typedef unsigned short u16x4 __attribute__((ext_vector_type(4)));

static __device__ __forceinline__ f32x4 mfma16(s16x8 a, s16x8 b, f32x4 c) {
    return __builtin_amdgcn_mfma_f32_16x16x32_bf16(
        __builtin_bit_cast(bf16x8, a), __builtin_bit_cast(bf16x8, b), c, 0, 0, 0);
}

// f32 -> bf16 round-to-nearest-even
static __device__ __forceinline__ unsigned short f2b(float f) {
    union { float f; unsigned u; } v; v.f = f;
    unsigned r = v.u + 0x7FFFu + ((v.u >> 16) & 1u);
    return (unsigned short)(r >> 16);
}

// load 8 consecutive f32 (32B-aligned) and convert to a bf16 MFMA fragment
static __device__ __forceinline__ s16x8 cvt8(const float* __restrict__ p) {
    const float4 a = *(const float4*)p;
    const float4 b = *(const float4*)(p + 4);
    s16x8 r;
    r[0] = (short)f2b(a.x); r[1] = (short)f2b(a.y);
    r[2] = (short)f2b(a.z); r[3] = (short)f2b(a.w);
    r[4] = (short)f2b(b.x); r[5] = (short)f2b(b.y);
    r[6] = (short)f2b(b.z); r[7] = (short)f2b(b.w);
    return r;
}

// ---------------- kernel 1: MFMA projections, 512-thread blocks -----------
// blocks [0,64):  qs for 32 x-rows each; [64,128): ks + vT for 32 c-rows.
// 8 waves; wave w covers e-cols [w*32, w*32+32) (2 n-tiles) -> full e range
// per block, so qs/ks come out complete (no partials).
__global__ __launch_bounds__(512) void k_proj(
    const float* __restrict__ x, const float* __restrict__ c,
    const float* __restrict__ Wq, const float* __restrict__ bq,
    const float* __restrict__ Wk, const float* __restrict__ Wr,
    const float* __restrict__ Wv, const float* __restrict__ bv,
    float* __restrict__ qs, float* __restrict__ ks,
    unsigned short* __restrict__ vT)
{
    __shared__ float red[8][32];
    const int tid  = threadIdx.x;
    const int lane = tid & 63, w = tid >> 6;      // w in [0,8)
    const int li   = lane & 15, g = lane >> 4;
    const bool isk = blockIdx.x >= 64;
    const int idx  = blockIdx.x & 63;
    const int row0 = idx << 5;                    // 32 rows per block
    const float* __restrict__ src = isk ? c : x;

    // A fragments for 2 row-tiles: lane supplies A[i=li][k=g*8+t]
    s16x8 af[2][8];
    #pragma unroll
    for (int rt = 0; rt < 2; ++rt) {
        const float* ap = src + (size_t)(row0 + rt * 16 + li) * DD + g * 8;
        #pragma unroll
        for (int kk = 0; kk < 8; ++kk) af[rt][kk] = cvt8(ap + kk * 32);
    }

    const int e_base = w * 32 + li;

    if (!isk) {
        f32x4 acc[2][2];   // [rt][nt]
        const float* bp[2];
        #pragma unroll
        for (int nt = 0; nt < 2; ++nt) {
            acc[0][nt] = (f32x4){0.f, 0.f, 0.f, 0.f};
            acc[1][nt] = (f32x4){0.f, 0.f, 0.f, 0.f};
            bp[nt] = Wq + (size_t)(e_base + nt * 16) * DD + g * 8;
        }
        #pragma unroll
        for (int kk = 0; kk < 8; ++kk) {
            const s16x8 b0 = cvt8(bp[0] + kk * 32);
            const s16x8 b1 = cvt8(bp[1] + kk * 32);
            #pragma unroll
            for (int rt = 0; rt < 2; ++rt) {
                acc[rt][0] = mfma16(af[rt][kk], b0, acc[rt][0]);
                acc[rt][1] = mfma16(af[rt][kk], b1, acc[rt][1]);
            }
        }
        float p[2][4] = {{0.f,0.f,0.f,0.f},{0.f,0.f,0.f,0.f}};
        #pragma unroll
        for (int nt = 0; nt < 2; ++nt) {
            const int e = e_base + nt * 16;
            const float bqe = bq[e], wre = Wr[e];
            #pragma unroll
            for (int rt = 0; rt < 2; ++rt)
                #pragma unroll
                for (int r = 0; r < 4; ++r)
                    p[rt][r] += wre * tanhf(acc[rt][nt][r] + bqe);
        }
        #pragma unroll
        for (int rt = 0; rt < 2; ++rt)
            #pragma unroll
            for (int r = 0; r < 4; ++r) {
                p[rt][r] += __shfl_xor(p[rt][r], 1);
                p[rt][r] += __shfl_xor(p[rt][r], 2);
                p[rt][r] += __shfl_xor(p[rt][r], 4);
                p[rt][r] += __shfl_xor(p[rt][r], 8);
            }
        if (li == 0)
            #pragma unroll
            for (int rt = 0; rt < 2; ++rt)
                #pragma unroll
                for (int r = 0; r < 4; ++r)
                    red[w][rt * 16 + g * 4 + r] = p[rt][r];
        __syncthreads();
        if (tid < 32) {
            float s = 0.f;
            #pragma unroll
            for (int ww = 0; ww < 8; ++ww) s += red[ww][tid];
            qs[row0 + tid] = s;
        }
    } else {
        f32x4 ak[2][2], av[2][2];
        const float* bpk[2];
        const float* bpv[2];
        #pragma unroll
        for (int nt = 0; nt < 2; ++nt) {
            ak[0][nt] = (f32x4){0.f,0.f,0.f,0.f}; ak[1][nt] = (f32x4){0.f,0.f,0.f,0.f};
            av[0][nt] = (f32x4){0.f,0.f,0.f,0.f}; av[1][nt] = (f32x4){0.f,0.f,0.f,0.f};
            bpk[nt] = Wk + (size_t)(e_base + nt * 16) * DD + g * 8;
            bpv[nt] = Wv + (size_t)(e_base + nt * 16) * DD + g * 8;
        }
        #pragma unroll
        for (int kk = 0; kk < 8; ++kk) {
            const s16x8 k0 = cvt8(bpk[0] + kk * 32);
            const s16x8 k1 = cvt8(bpk[1] + kk * 32);
            const s16x8 v0 = cvt8(bpv[0] + kk * 32);
            const s16x8 v1 = cvt8(bpv[1] + kk * 32);
            #pragma unroll
            for (int rt = 0; rt < 2; ++rt) {
                ak[rt][0] = mfma16(af[rt][kk], k0, ak[rt][0]);
                ak[rt][1] = mfma16(af[rt][kk], k1, ak[rt][1]);
                av[rt][0] = mfma16(af[rt][kk], v0, av[rt][0]);
                av[rt][1] = mfma16(af[rt][kk], v1, av[rt][1]);
            }
        }

        // vT[b][e][m] bf16: lane holds m-rows (m0 + rt*16 + 4g + r) for col e
        const int b  = row0 >> 9;
        const int m0 = row0 & 511;
        unsigned short* vTb = vT + (size_t)b * (DD * MM);
        #pragma unroll
        for (int nt = 0; nt < 2; ++nt) {
            const int e = e_base + nt * 16;
            const float bve = bv[e];
            #pragma unroll
            for (int rt = 0; rt < 2; ++rt) {
                u16x4 o;
                #pragma unroll
                for (int r = 0; r < 4; ++r)
                    o[r] = f2b((av[rt][nt][r] + bve) * 0.0625f);  // 1/sqrt(256)
                *(u16x4*)(vTb + (size_t)e * MM + m0 + rt * 16 + g * 4) = o;
            }
        }

        float p[2][4] = {{0.f,0.f,0.f,0.f},{0.f,0.f,0.f,0.f}};
        #pragma unroll
        for (int nt = 0; nt < 2; ++nt) {
            const int e = e_base + nt * 16;
            const float wre = Wr[e];
            #pragma unroll
            for (int rt = 0; rt < 2; ++rt)
                #pragma unroll
                for (int r = 0; r < 4; ++r)
                    p[rt][r] += wre * tanhf(ak[rt][nt][r]);
        }
        #pragma unroll
        for (int rt = 0; rt < 2; ++rt)
            #pragma unroll
            for (int r = 0; r < 4; ++r) {
                p[rt][r] += __shfl_xor(p[rt][r], 1);
                p[rt][r] += __shfl_xor(p[rt][r], 2);
                p[rt][r] += __shfl_xor(p[rt][r], 4);
                p[rt][r] += __shfl_xor(p[rt][r], 8);
            }
        if (li == 0)
            #pragma unroll
            for (int rt = 0; rt < 2; ++rt)
                #pragma unroll
                for (int r = 0; r < 4; ++r)
                    red[w][rt * 16 + g * 4 + r] = p[rt][r];
        __syncthreads();
        if (tid < 32) {
            float s = 0.f;
            #pragma unroll
            for (int ww = 0; ww < 8; ++ww) s += red[ww][tid];
            ks[row0 + tid] = s;
        }
    }
}

// ---------------- kernel 2: scores + PV (MFMA) + residual + LayerNorm -----
// 256 blocks x 8 n-rows x 512 threads (8 waves/CU). Score tile bf16
// XOR-swizzled in LDS. Wave w covers e-cols [w*32, w*32+32) (2 n-tiles).
// MFMA A-tile rows 8..15 are stale LDS garbage; their D-rows never read.
__global__ __launch_bounds__(512) void k_main(
    const float* __restrict__ x, const float* __restrict__ mask,
    const float* __restrict__ qs, const float* __restrict__ ks,
    const unsigned short* __restrict__ vT,
    const float* __restrict__ gamma, const float* __restrict__ beta,
    float* __restrict__ out)
{
    __shared__ unsigned short w_lds[16][512];   // 16 KB (rows 0..7 written)
    __shared__ float ksm[MM];                   // 2 KB
    __shared__ float h_lds[16][264];            // 16.9 KB
    const int tid  = threadIdx.x;
    const int lane = tid & 63, w = tid >> 6;    // w in [0,8)
    const int li   = lane & 15, g = lane >> 4;
    const int n0g  = blockIdx.x << 3;           // 8 rows per block
    const int b    = n0g >> 9;

    ksm[tid] = ks[(b << 9) + tid];
    __syncthreads();

    // scores rows 0..7 -> bf16 swizzled LDS (byte ^= (row&7)<<4), 8 m/thread
    char* wbase = (char*)w_lds;
    const float* __restrict__ mrow = mask + (size_t)n0g * MM;
    #pragma unroll
    for (int it = 0; it < 2; ++it) {
        const int L = (it << 11) + (tid << 2);
        const int i = L >> 9;
        const int m = L & 511;
        const float qv = qs[n0g + i];
        const float4 mk = *(const float4*)(mrow + (size_t)i * MM + m);
        const float4 kv = *(const float4*)&ksm[m];
        u16x4 o;
        o[0] = f2b(fmaxf(tanhf(qv + kv.x), 0.f) * mk.x);
        o[1] = f2b(fmaxf(tanhf(qv + kv.y), 0.f) * mk.y);
        o[2] = f2b(fmaxf(tanhf(qv + kv.z), 0.f) * mk.z);
        o[3] = f2b(fmaxf(tanhf(qv + kv.w), 0.f) * mk.w);
        *(u16x4*)(wbase + (i << 10) + ((m << 1) ^ ((i & 7) << 4))) = o;
    }
    __syncthreads();

    // PV: wave w covers e-cols [w*32, w*32+32), K = 512 (16 k-steps)
    f32x4 acc[2];
    const unsigned short* vp[2];
    #pragma unroll
    for (int nt = 0; nt < 2; ++nt) {
        acc[nt] = (f32x4){0.f, 0.f, 0.f, 0.f};
        vp[nt] = vT + (size_t)b * (DD * MM)
                    + (size_t)(w * 32 + nt * 16 + li) * MM + g * 8;
    }
    const char* arow = wbase + (li << 10);
    const int aswz = (li & 7) << 4;
    #pragma unroll
    for (int kk = 0; kk < 16; ++kk) {
        const s16x8 a = *(const s16x8*)(arow + (((kk << 6) + (g << 4)) ^ aswz));
        acc[0] = mfma16(a, *(const s16x8*)(vp[0] + kk * 32), acc[0]);
        acc[1] = mfma16(a, *(const s16x8*)(vp[1] + kk * 32), acc[1]);
    }

    // scatter partial h: lane holds D-rows 4g+r, col e (rows 0..7 consumed)
    #pragma unroll
    for (int nt = 0; nt < 2; ++nt) {
        const int e = w * 32 + nt * 16 + li;
        #pragma unroll
        for (int r = 0; r < 4; ++r)
            h_lds[g * 4 + r][e] = acc[nt][r];
    }
    __syncthreads();

    // LN: wave w owns row w; lane owns 4 contiguous d
    {
        const int row = w;
        const float4 gm = ((const float4*)gamma)[lane];
        const float4 bt = ((const float4*)beta)[lane];
        const float4 hv = *(const float4*)&h_lds[row][lane << 2];
        const float4 xv = *(const float4*)(x + ((size_t)(n0g + row)) * DD + (lane << 2));
        float4 h;
        h.x = xv.x + hv.x; h.y = xv.y + hv.y;
        h.z = xv.z + hv.z; h.w = xv.w + hv.w;
        float s  = h.x + h.y + h.z + h.w;
        float s2 = h.x * h.x + h.y * h.y + h.z * h.z + h.w * h.w;
        #pragma unroll
        for (int off = 32; off; off >>= 1) {
            s  += __shfl_xor(s, off);
            s2 += __shfl_xor(s2, off);
        }
        const float mean = s * (1.0f / DD);
        const float var  = s2 * (1.0f / DD) - mean * mean;
        const float inv  = rsqrtf(var + 1e-5f);
        float4 o;
        o.x = (h.x - mean) * inv * gm.x + bt.x;
        o.y = (h.y - mean) * inv * gm.y + bt.y;
        o.z = (h.z - mean) * inv * gm.z + bt.z;
        o.w = (h.w - mean) * inv * gm.w + bt.w;
        *(float4*)(out + ((size_t)(n0g + row)) * DD + (lane << 2)) = o;
    }
}

extern "C" void kernel_launch(void* const* d_in, const int* in_sizes, int n_in,
                              void* d_out, int out_size, void* d_ws, size_t ws_size,
                              hipStream_t stream) {
    const float* x     = (const float*)d_in[0];
    const float* c     = (const float*)d_in[1];
    const float* mask  = (const float*)d_in[2];
    const float* Wq    = (const float*)d_in[3];
    const float* bq    = (const float*)d_in[4];
    const float* Wk    = (const float*)d_in[5];
    const float* Wr    = (const float*)d_in[6];
    const float* Wv    = (const float*)d_in[7];
    const float* bv    = (const float*)d_in[8];
    const float* gamma = (const float*)d_in[9];
    const float* beta  = (const float*)d_in[10];
    float* out = (float*)d_out;

    float* ws = (float*)d_ws;
    float* qs  = ws;                                    // 2048 f32
    float* ksb = ws + 2048;                             // 2048 f32
    unsigned short* vT = (unsigned short*)(ws + 4096);  // 524288 bf16 [b][e][m]

    k_proj<<<128, 512, 0, stream>>>(x, c, Wq, bq, Wk, Wr, Wv, bv, qs, ksb, vT);
    k_main<<<256, 512, 0, stream>>>(x, mask, qs, ksb, vT, gamma, beta, out);
}